// Round 5
// baseline (109.632 us; speedup 1.0000x reference)
//
#include <hip/hip_runtime.h>
#include <math.h>

#define SH_C0     0.28209479177387814f
#define EPS2D     0.3f
#define NEARZ     0.01f
#define ALPHA_MIN (1.0f/255.0f)
#define ALPHA_MAX 0.999f
#define LOG2E     1.4426950408889634f

// ---------------------------------------------------------------------------
// Fused preprocess + stable-rank + scatter. One 64-lane wave per gaussian.
// Record (12 floats, 48B, float4-aligned), indexed by depth rank:
//   [0] u  [1] v  [2] A2'=-0.5*conA*log2e... (stored positive, negated in use)
//   {u, v, 0.5*conA*L2E, conB*L2E, 0.5*conC*L2E, op, cr, cg, cb, rx, ry, 0}
// rx, ry = conservative half-extents of the alpha >= 1/255 ellipse (+0.5 pad)
// so tile culling is exact: outside the bbox the reference zeroes alpha.
// Invalid (z<=NEAR or det<=0) or op<1/255 gaussians: u=v=-1e9, rx=ry=0 ->
// excluded from every tile == alpha 0 everywhere (matches reference).
// Rank key = (zc > NEAR ? zc : +inf), stable tie-break j<i: permutation
// matches jnp.argsort exactly for all contributing gaussians.
// ---------------------------------------------------------------------------
__global__ __launch_bounds__(256) void prep_rank_kernel(
        const float* __restrict__ means,
        const float* __restrict__ quats,
        const float* __restrict__ scales,
        const float* __restrict__ opacities,
        const float* __restrict__ sh,
        const float* __restrict__ vm,
        const float* __restrict__ K,
        float* __restrict__ sorted,
        int N) {
    int wave = blockIdx.x * 4 + (threadIdx.x >> 6);
    int lane = threadIdx.x & 63;
    if (wave >= N) return;
    int i = wave;

    float r00=vm[0], r01=vm[1], r02=vm[2],  t0=vm[3];
    float r10=vm[4], r11=vm[5], r12=vm[6],  t1=vm[7];
    float r20=vm[8], r21=vm[9], r22=vm[10], t2=vm[11];

    // --- stable rank: count keys strictly smaller (ties: j < i) ---
    float mx = means[3*i+0], my = means[3*i+1], mz = means[3*i+2];
    float zci = r20*mx + r21*my + r22*mz + t2;
    float keyi = (zci > NEARZ) ? zci : INFINITY;
    int cnt = 0;
    for (int j = lane; j < N; j += 64) {
        float ax = means[3*j+0], ay = means[3*j+1], az = means[3*j+2];
        float zcj = r20*ax + r21*ay + r22*az + t2;
        float keyj = (zcj > NEARZ) ? zcj : INFINITY;
        cnt += (keyj < keyi) || (keyj == keyi && j < i);
    }
    #pragma unroll
    for (int off = 32; off > 0; off >>= 1)
        cnt += __shfl_xor(cnt, off, 64);

    // --- preprocess (redundant across lanes; uniform loads) ---
    float qw = quats[4*i+0], qx = quats[4*i+1], qy = quats[4*i+2], qz = quats[4*i+3];
    float rqn = rsqrtf(qw*qw + qx*qx + qy*qy + qz*qz);
    qw *= rqn; qx *= rqn; qy *= rqn; qz *= rqn;

    float R00 = 1.f - 2.f*(qy*qy + qz*qz);
    float R01 = 2.f*(qx*qy - qw*qz);
    float R02 = 2.f*(qx*qz + qw*qy);
    float R10 = 2.f*(qx*qy + qw*qz);
    float R11 = 1.f - 2.f*(qx*qx + qz*qz);
    float R12 = 2.f*(qy*qz - qw*qx);
    float R20 = 2.f*(qx*qz - qw*qy);
    float R21 = 2.f*(qy*qz + qw*qx);
    float R22 = 1.f - 2.f*(qx*qx + qy*qy);

    float s0 = fminf(expf(scales[3*i+0]), 10.f);
    float s1 = fminf(expf(scales[3*i+1]), 10.f);
    float s2 = fminf(expf(scales[3*i+2]), 10.f);

    float M00=R00*s0, M01=R01*s1, M02=R02*s2;
    float M10=R10*s0, M11=R11*s1, M12=R12*s2;
    float M20=R20*s0, M21=R21*s1, M22=R22*s2;

    float c00 = M00*M00 + M01*M01 + M02*M02;
    float c01 = M00*M10 + M01*M11 + M02*M12;
    float c02 = M00*M20 + M01*M21 + M02*M22;
    float c11 = M10*M10 + M11*M11 + M12*M12;
    float c12 = M10*M20 + M11*M21 + M12*M22;
    float c22 = M20*M20 + M21*M21 + M22*M22;

    float xc = r00*mx + r01*my + r02*mz + t0;
    float yc = r10*mx + r11*my + r12*mz + t1;
    float zc = zci;

    float T00 = r00*c00 + r01*c01 + r02*c02;
    float T01 = r00*c01 + r01*c11 + r02*c12;
    float T02 = r00*c02 + r01*c12 + r02*c22;
    float T10 = r10*c00 + r11*c01 + r12*c02;
    float T11 = r10*c01 + r11*c11 + r12*c12;
    float T12 = r10*c02 + r11*c12 + r12*c22;
    float T20 = r20*c00 + r21*c01 + r22*c02;
    float T21 = r20*c01 + r21*c11 + r22*c12;
    float T22 = r20*c02 + r21*c12 + r22*c22;
    float V00 = T00*r00 + T01*r01 + T02*r02;
    float V01 = T00*r10 + T01*r11 + T02*r12;
    float V02 = T00*r20 + T01*r21 + T02*r22;
    float V11 = T10*r10 + T11*r11 + T12*r12;
    float V12 = T10*r20 + T11*r21 + T12*r22;
    float V22 = T20*r20 + T21*r21 + T22*r22;

    float fx = K[0], cx = K[2], fy = K[4], cy = K[5];

    bool valid = zc > NEARZ;
    float zs = valid ? zc : 1.0f;
    float rz = 1.0f / zs;
    float u = fx*xc*rz + cx;
    float v = fy*yc*rz + cy;
    float J00 = fx*rz;
    float J02 = -fx*xc*rz*rz;
    float J11 = fy*rz;
    float J12 = -fy*yc*rz*rz;

    float a = J00*J00*V00 + 2.f*J00*J02*V02 + J02*J02*V22 + EPS2D;
    float b = J00*(J11*V01 + J12*V02) + J02*(J11*V12 + J12*V22);
    float c = J11*J11*V11 + 2.f*J11*J12*V12 + J12*J12*V22 + EPS2D;
    float det = a*c - b*b;
    valid = valid && (det > 0.f);
    float det_s = valid ? det : 1.0f;
    float conA =  c / det_s;
    float conB = -b / det_s;
    float conC =  a / det_s;

    float op  = 1.0f / (1.0f + expf(-opacities[i]));
    float cr = fmaxf(sh[3*i+0]*SH_C0 + 0.5f, 0.f);
    float cg = fmaxf(sh[3*i+1]*SH_C0 + 0.5f, 0.f);
    float cb = fmaxf(sh[3*i+2]*SH_C0 + 0.5f, 0.f);

    // conservative alpha>=1/255 ellipse half-extents
    float smax = logf(op * 255.0f);                 // sigma budget
    bool vis = valid && (smax > 0.f);
    float denom = conA*conC - conB*conB;            // = 1/det(cov2d) > 0
    float rxe = 0.f, rye = 0.f;
    if (vis) {
        float inv = 2.f * smax / denom;
        rxe = sqrtf(fmaxf(inv * conC, 0.f)) + 0.5f; // +0.5px conservative pad
        rye = sqrtf(fmaxf(inv * conA, 0.f)) + 0.5f;
    }

    float e0, e1, e2, e3, e4, e5;
    if (vis) {
        e0 = u; e1 = v;
        e2 = 0.5f*conA*LOG2E; e3 = conB*LOG2E; e4 = 0.5f*conC*LOG2E;
        e5 = op;
    } else {
        e0 = -1.0e9f; e1 = -1.0e9f; e2=0; e3=0; e4=0; e5=0;
    }

    if (lane < 12) {
        float val;
        switch (lane) {
            case 0:  val = e0;  break;
            case 1:  val = e1;  break;
            case 2:  val = e2;  break;
            case 3:  val = e3;  break;
            case 4:  val = e4;  break;
            case 5:  val = e5;  break;
            case 6:  val = cr;  break;
            case 7:  val = cg;  break;
            case 8:  val = cb;  break;
            case 9:  val = rxe; break;
            case 10: val = rye; break;
            default: val = 0.f; break;
        }
        sorted[12*(size_t)cnt + lane] = val;
    }
}

// ---------------------------------------------------------------------------
// Tiled render: 1 block per 8x8-px tile (16x16 tiles), 512 threads = 8 waves.
// Wave w owns 4 contiguous 64-gaussian words of the depth-sorted list
// (order-preserving segments of 256). Per word: lanes ballot the tile-vs-
// ellipse-bbox test -> uniform u64 mask; iterate set bits (ctz) so the
// gaussian record address is wave-uniform (scalar loads). Per-wave (C,T)
// partials folded in depth order via LDS; written directly to out.
// Culling is conservative => identical output to the uncullled version.
// ---------------------------------------------------------------------------
__global__ __launch_bounds__(512, 2) void render_tile_kernel(
        const float4* __restrict__ rec,
        float* __restrict__ out,
        int N) {
    __shared__ float4 part[8][64];
    int tid  = threadIdx.x;
    int lane = tid & 63;
    int w    = tid >> 6;
    int t    = blockIdx.x;
    int tx   = (t & 15) << 3;
    int ty   = (t >> 4) << 3;

    float px = (float)(tx + (lane & 7)) + 0.5f;
    float py = (float)(ty + (lane >> 3)) + 0.5f;
    float x0 = (float)tx + 0.5f, x1 = (float)tx + 7.5f;
    float y0 = (float)ty + 0.5f, y1 = (float)ty + 7.5f;

    int nwords = (N + 63) >> 6;
    int wpw    = (nwords + 7) >> 3;     // words per wave

    float accr = 0.f, accg = 0.f, accb = 0.f, T = 1.f;
    for (int k = 0; k < wpw; ++k) {
        int word = w * wpw + k;
        int base = word << 6;
        int g = base + lane;
        bool pred = false;
        if (g < N) {
            float4 a0 = rec[3*(size_t)g];       // u, v, -, -
            float4 a2 = rec[3*(size_t)g + 2];   // cb, rx, ry, -
            pred = (a0.x + a2.y >= x0) && (a0.x - a2.y <= x1) &&
                   (a0.y + a2.z >= y0) && (a0.y - a2.z <= y1);
        }
        unsigned long long m = __ballot(pred);
        while (m) {
            int b = (int)__builtin_ctzll(m);
            m &= (m - 1);
            const float4* r = rec + 3*(size_t)(base + b);  // uniform -> s_load
            float4 r0 = r[0];            // u, v, A2', B'
            float4 r1 = r[1];            // C2', op, cr, cg
            float  cb = r[2].x;
            float dx = px - r0.x, dy = py - r0.y;
            float t2  = fmaf(r0.z, dx, r0.w * dy);
            float arg = fmaf(-r1.x, dy*dy, -dx*t2);        // -sigma*log2e
            float al  = r1.y * __builtin_amdgcn_exp2f(arg);
            al = fminf(al, ALPHA_MAX);
            al = (al >= ALPHA_MIN) ? al : 0.f;
            float wg = T * al;
            accr = fmaf(wg, r1.z, accr);
            accg = fmaf(wg, r1.w, accg);
            accb = fmaf(wg, cb,  accb);
            T = fmaf(-al, T, T);
        }
    }
    part[w][lane] = make_float4(accr, accg, accb, T);
    __syncthreads();

    if (tid < 64) {
        float R = 0.f, G = 0.f, B = 0.f, Tr = 1.f;
        #pragma unroll
        for (int s = 0; s < 8; ++s) {
            float4 q = part[s][tid];
            R  = fmaf(Tr, q.x, R);
            G  = fmaf(Tr, q.y, G);
            B  = fmaf(Tr, q.z, B);
            Tr *= q.w;
        }
        int x = tx + (tid & 7);
        int y = ty + (tid >> 3);
        int p = y * 128 + x;
        out[3*(size_t)p+0] = R;
        out[3*(size_t)p+1] = G;
        out[3*(size_t)p+2] = B;
    }
}

extern "C" void kernel_launch(void* const* d_in, const int* in_sizes, int n_in,
                              void* d_out, int out_size, void* d_ws, size_t ws_size,
                              hipStream_t stream) {
    const float* means     = (const float*)d_in[0];
    const float* quats     = (const float*)d_in[1];
    const float* scales    = (const float*)d_in[2];
    const float* opacities = (const float*)d_in[3];
    const float* sh        = (const float*)d_in[4];
    const float* vm        = (const float*)d_in[5];
    const float* K         = (const float*)d_in[6];

    int N = in_sizes[0] / 3;   // gaussians
    // int P = out_size / 3;   // 16384 pixels = 128x128 (fixed by problem)

    float* sorted = (float*)d_ws;   // N*12 floats

    prep_rank_kernel<<<(N + 3) / 4, 256, 0, stream>>>(
        means, quats, scales, opacities, sh, vm, K, sorted, N);
    render_tile_kernel<<<256, 512, 0, stream>>>(
        (const float4*)sorted, (float*)d_out, N);
}